// Round 1
// baseline (1889.322 us; speedup 1.0000x reference)
//
#include <hip/hip_runtime.h>
#include <math.h>

// Problem constants (from reference setup_inputs)
#define BB 16
#define CC 128
#define LL 16384
#define SS 128      // sqrt(L)
#define LK 4096     // (S/2)^2
#define NHEAD 8
#define DH 16

__device__ __forceinline__ float gelu_f(float x) {
    return 0.5f * x * (1.0f + erff(x * 0.70710678118654752f));
}

// Reduce s1,s2 across the block; result valid in thread 0.
__device__ __forceinline__ void block_reduce2(float& s1, float& s2) {
    #pragma unroll
    for (int off = 32; off; off >>= 1) {
        s1 += __shfl_down(s1, off);
        s2 += __shfl_down(s2, off);
    }
    __shared__ float red[2][4];
    int wid = threadIdx.x >> 6, lid = threadIdx.x & 63;
    if (lid == 0) { red[0][wid] = s1; red[1][wid] = s2; }
    __syncthreads();
    if (threadIdx.x == 0) {
        int nw = blockDim.x >> 6;
        float a = 0.f, b = 0.f;
        for (int i = 0; i < nw; i++) { a += red[0][i]; b += red[1][i]; }
        s1 = a; s2 = b;
    }
}

// ---------------------------------------------------------------------------
// K1: per-(branch,channel) sum/sumsq of depthwise-conv output (recomputed).
// grid: 3*2048 blocks (branch, n, c), 256 threads.
__global__ void k_dw_stats(const float* __restrict__ x, const float* __restrict__ dw_w,
                           float* __restrict__ stats /* [3][128][2] */) {
    int bx = blockIdx.x;
    int br = bx >> 11;          // /2048
    int r  = bx & 2047;
    int c  = r & 127;
    int n  = r >> 7;
    int st = (br == 0) ? 1 : 2;
    int sh = (br == 0) ? 7 : 6;     // log2(So)
    int So = 1 << sh;
    int npos = So * So;
    float w[9];
    const float* wp = dw_w + (br * CC + c) * 9;
    #pragma unroll
    for (int i = 0; i < 9; i++) w[i] = wp[i];
    const float* xim = x + ((size_t)n * CC + c) * (size_t)LL;
    float s1 = 0.f, s2 = 0.f;
    for (int e = threadIdx.x; e < npos; e += 256) {
        int oh = e >> sh, ow = e & (So - 1);
        int ihb = oh * st - 1, iwb = ow * st - 1;
        float acc = 0.f;
        #pragma unroll
        for (int kh = 0; kh < 3; kh++) {
            int ih = ihb + kh;
            if (ih < 0 || ih > 127) continue;
            #pragma unroll
            for (int kw = 0; kw < 3; kw++) {
                int iw = iwb + kw;
                if (iw < 0 || iw > 127) continue;
                acc += w[kh * 3 + kw] * xim[ih * SS + iw];
            }
        }
        s1 += acc; s2 += acc * acc;
    }
    block_reduce2(s1, s2);
    if (threadIdx.x == 0) {
        atomicAdd(&stats[(br * CC + c) * 2 + 0], s1);
        atomicAdd(&stats[(br * CC + c) * 2 + 1], s2);
    }
}

// ---------------------------------------------------------------------------
// K2: fold BN2d into pointwise conv: effW_t[br][c][o], effB[br][o].
// grid: 3*128 blocks (branch,o), 128 threads (c).
__global__ void k_finalize_dw(const float* __restrict__ stats, const float* __restrict__ pw_w,
                              const float* __restrict__ pw_b, const float* __restrict__ bn2_g,
                              const float* __restrict__ bn2_b,
                              float* __restrict__ effW_t, float* __restrict__ effB) {
    int br = blockIdx.x >> 7;
    int o  = blockIdx.x & 127;
    int c  = threadIdx.x;
    float N = (br == 0) ? 262144.f : 65536.f;
    float s1 = stats[(br * CC + c) * 2 + 0];
    float s2 = stats[(br * CC + c) * 2 + 1];
    float m = s1 / N;
    float v = s2 / N - m * m;
    float sc = rsqrtf(v + 1e-5f);
    float A  = bn2_g[br * CC + c] * sc;
    float Bc = bn2_b[br * CC + c] - m * A;
    float w  = pw_w[((size_t)br * CC + o) * CC + c];
    effW_t[((size_t)br * CC + c) * CC + o] = w * A;
    float pb = w * Bc, dummy = 0.f;
    block_reduce2(pb, dummy);
    if (threadIdx.x == 0) effB[br * CC + o] = pw_b[br * CC + o] + pb;
}

// ---------------------------------------------------------------------------
// K3: k & v branches (stride 2): dw(recompute)->LDS, pointwise, gelu.
// out layout [b][p][c]. grid: 2048 blocks, 256 threads.
__global__ void k_branch_kv(const float* __restrict__ x, const float* __restrict__ dw_w,
                            const float* __restrict__ effW_t, const float* __restrict__ effB,
                            float* __restrict__ k_buf, float* __restrict__ v_buf) {
    int bx = blockIdx.x;
    int br = 1 + (bx >> 10);
    int r = bx & 1023;
    int b = r >> 6;
    int oh = r & 63;
    __shared__ float dwt[CC][64];
    int tid = threadIdx.x;
    int ow = tid & 63;
    {
        int ihb = oh * 2 - 1, iwb = ow * 2 - 1;
        for (int kk = 0; kk < 32; kk++) {
            int c = (tid >> 6) + (kk << 2);
            const float* wp = dw_w + (br * CC + c) * 9;
            const float* xim = x + ((size_t)b * CC + c) * (size_t)LL;
            float acc = 0.f;
            #pragma unroll
            for (int kh = 0; kh < 3; kh++) {
                int ih = ihb + kh;
                if (ih < 0 || ih > 127) continue;
                #pragma unroll
                for (int kw = 0; kw < 3; kw++) {
                    int iw = iwb + kw;
                    if (iw < 0 || iw > 127) continue;
                    acc += wp[kh * 3 + kw] * xim[ih * SS + iw];
                }
            }
            dwt[c][ow] = acc;
        }
    }
    __syncthreads();
    int og = tid >> 6, ob = og * 32;
    float acc[32];
    #pragma unroll
    for (int i = 0; i < 32; i++) acc[i] = effB[br * CC + ob + i];
    for (int c = 0; c < CC; c++) {
        float dv = dwt[c][ow];
        const float4* w4 = (const float4*)(effW_t + ((size_t)br * CC + c) * CC + ob);
        #pragma unroll
        for (int i = 0; i < 8; i++) {
            float4 w = w4[i];
            acc[4*i+0] += w.x * dv; acc[4*i+1] += w.y * dv;
            acc[4*i+2] += w.z * dv; acc[4*i+3] += w.w * dv;
        }
    }
    float* outb = (br == 1) ? k_buf : v_buf;
    int p = oh * 64 + ow;
    float4* dst = (float4*)(outb + ((size_t)b * LK + p) * CC + ob);
    #pragma unroll
    for (int i = 0; i < 8; i++) {
        float4 o4;
        o4.x = gelu_f(acc[4*i+0]); o4.y = gelu_f(acc[4*i+1]);
        o4.z = gelu_f(acc[4*i+2]); o4.w = gelu_f(acc[4*i+3]);
        dst[i] = o4;
    }
}

// ---------------------------------------------------------------------------
// K4: kv_un[b,h,d,e] = sum_n exp(k[n,d]) * v[n,e]; ssum[b,h,d] = sum_n exp(k[n,d]).
// (k values are bounded, so no max-subtraction needed.)
// grid: B*H*4 = 512 blocks (4 slices of n), 256 threads, thread=(d,e).
__global__ void k_kv_accum(const float* __restrict__ k_buf, const float* __restrict__ v_buf,
                           float* __restrict__ kv_un, float* __restrict__ ssum) {
    int bx = blockIdx.x;
    int b = bx >> 5;
    int h = (bx >> 2) & 7;
    int sl = bx & 3;
    int n0 = sl * 1024;
    __shared__ float kch[64][16];
    __shared__ float vch[64][16];
    int tid = threadIdx.x;
    int d = tid >> 4, e = tid & 15;
    float acc = 0.f, ss = 0.f;
    for (int ch = 0; ch < 16; ch++) {
        int base = n0 + ch * 64;
        {
            int rr = tid >> 2, c4 = (tid & 3) * 4;
            const float* kp = k_buf + ((size_t)b * LK + base + rr) * CC + h * DH + c4;
            const float* vp = v_buf + ((size_t)b * LK + base + rr) * CC + h * DH + c4;
            float4 kf = *(const float4*)kp;
            float4 vf = *(const float4*)vp;
            kch[rr][c4+0] = __expf(kf.x); kch[rr][c4+1] = __expf(kf.y);
            kch[rr][c4+2] = __expf(kf.z); kch[rr][c4+3] = __expf(kf.w);
            vch[rr][c4+0] = vf.x; vch[rr][c4+1] = vf.y;
            vch[rr][c4+2] = vf.z; vch[rr][c4+3] = vf.w;
        }
        __syncthreads();
        #pragma unroll 8
        for (int rr = 0; rr < 64; rr++) {
            float ek = kch[rr][d];
            acc += ek * vch[rr][e];
            ss += ek;
        }
        __syncthreads();
    }
    atomicAdd(&kv_un[(((size_t)b * NHEAD + h) * DH + d) * DH + e], acc);
    if (e == 0) atomicAdd(&ssum[((size_t)b * NHEAD + h) * DH + d], ss);
}

// K4b: kv = kv_un / ssum[d]. grid 128 x 256.
__global__ void k_kv_div(const float* __restrict__ kv_un, const float* __restrict__ ssum,
                         float* __restrict__ kv) {
    int i = blockIdx.x * 256 + threadIdx.x;
    kv[i] = kv_un[i] / ssum[i >> 4];
}

// ---------------------------------------------------------------------------
// K5: q branch + per-head softmax(dh) + att = qs@kv + weighted residual with x.
// Writes y1 [b][c][p]. grid: B*256 = 4096 blocks, 256 threads.
__global__ void k_branch_q(const float* __restrict__ x, const float* __restrict__ dw_w,
                           const float* __restrict__ effW_t, const float* __restrict__ effB,
                           const float* __restrict__ kv, const float* __restrict__ add_w,
                           float* __restrict__ y1) {
    int bx = blockIdx.x;
    int b = bx >> 8;
    int t = bx & 255;
    int oh = t >> 1;
    int ow0 = (t & 1) << 6;
    __shared__ float dwt[CC][64];
    __shared__ float kvs[NHEAD][DH][DH];
    int tid = threadIdx.x;
    {
        const float4* src = (const float4*)(kv + (size_t)b * 2048);
        float4* dst = (float4*)&kvs[0][0][0];
        dst[tid] = src[tid];
        dst[tid + 256] = src[tid + 256];
    }
    int ow = tid & 63;
    {
        int ihb = oh - 1, iwb = ow0 + ow - 1;
        for (int kk = 0; kk < 32; kk++) {
            int c = (tid >> 6) + (kk << 2);
            const float* wp = dw_w + c * 9;   // branch 0
            const float* xim = x + ((size_t)b * CC + c) * (size_t)LL;
            float acc = 0.f;
            #pragma unroll
            for (int kh = 0; kh < 3; kh++) {
                int ih = ihb + kh;
                if (ih < 0 || ih > 127) continue;
                #pragma unroll
                for (int kw = 0; kw < 3; kw++) {
                    int iw = iwb + kw;
                    if (iw < 0 || iw > 127) continue;
                    acc += wp[kh * 3 + kw] * xim[ih * SS + iw];
                }
            }
            dwt[c][ow] = acc;
        }
    }
    __syncthreads();
    int og = tid >> 6, ob = og * 32;
    float acc[32];
    #pragma unroll
    for (int i = 0; i < 32; i++) acc[i] = effB[ob + i];
    for (int c = 0; c < CC; c++) {
        float dv = dwt[c][ow];
        const float4* w4 = (const float4*)(effW_t + (size_t)c * CC + ob);
        #pragma unroll
        for (int i = 0; i < 8; i++) {
            float4 w = w4[i];
            acc[4*i+0] += w.x * dv; acc[4*i+1] += w.y * dv;
            acc[4*i+2] += w.z * dv; acc[4*i+3] += w.w * dv;
        }
    }
    #pragma unroll
    for (int i = 0; i < 32; i++) acc[i] = gelu_f(acc[i]);
    float wa0 = add_w[0], wa1 = add_w[1];
    float r0 = fmaxf(wa0, 0.f), r1 = fmaxf(wa1, 0.f);
    float inv = 1.f / (r0 + r1 + 1e-12f);
    float wn0 = r0 * inv, wn1 = r1 * inv;
    int p = oh * SS + ow0 + ow;
    const float* xcol = x + (size_t)b * (CC * (size_t)LL) + p;
    float* ycol = y1 + (size_t)b * (CC * (size_t)LL) + p;
    #pragma unroll
    for (int hl = 0; hl < 2; hl++) {
        float* a = acc + hl * 16;
        float mx = a[0];
        #pragma unroll
        for (int d = 1; d < 16; d++) mx = fmaxf(mx, a[d]);
        float ee[16]; float s = 0.f;
        #pragma unroll
        for (int d = 0; d < 16; d++) { ee[d] = __expf(a[d] - mx); s += ee[d]; }
        float is = 1.f / s;
        int h = og * 2 + hl;
        #pragma unroll
        for (int eo = 0; eo < 16; eo++) {
            float att = 0.f;
            #pragma unroll
            for (int d = 0; d < 16; d++) att += ee[d] * kvs[h][d][eo];
            att *= is;
            int cch = ob + hl * 16 + eo;
            float yv = wn0 * att + wn1 * xcol[(size_t)cch * LL];
            ycol[(size_t)cch * LL] = yv;
        }
    }
}

// ---------------------------------------------------------------------------
// Per-channel sum/sumsq over [B][C][L] buffer. grid: 128*32 blocks.
__global__ void k_chan_stats(const float* __restrict__ buf, float* __restrict__ stats) {
    int c = blockIdx.x >> 5;
    int s = blockIdx.x & 31;
    int b = s >> 1;
    int p0 = (s & 1) << 13;
    const float* src = buf + (size_t)b * (CC * (size_t)LL) + (size_t)c * LL + p0;
    float s1 = 0.f, s2 = 0.f;
    for (int i = threadIdx.x * 4; i < 8192; i += 1024) {
        float4 v = *(const float4*)(src + i);
        s1 += v.x + v.y + v.z + v.w;
        s2 += v.x * v.x + v.y * v.y + v.z * v.z + v.w * v.w;
    }
    block_reduce2(s1, s2);
    if (threadIdx.x == 0) {
        atomicAdd(&stats[c * 2 + 0], s1);
        atomicAdd(&stats[c * 2 + 1], s2);
    }
}

// ---------------------------------------------------------------------------
// fin1: BN1d(att) affine A1/B1; effW1 = W1*A1; effb1 = b1 + W1^T B1; W2T transpose.
// single block, 128 threads.
__global__ void k_fin1(const float* __restrict__ stats1, const float* __restrict__ bn1_g,
                       const float* __restrict__ bn1_b, const float* __restrict__ W1,
                       const float* __restrict__ b1, const float* __restrict__ W2,
                       float* __restrict__ A1B1, float* __restrict__ effW1,
                       float* __restrict__ effb1, float* __restrict__ W2T) {
    int t = threadIdx.x;
    const float N = 262144.f;
    float m = stats1[t * 2] / N;
    float v = stats1[t * 2 + 1] / N - m * m;
    float sc = rsqrtf(v + 1e-5f);
    float A = bn1_g[t] * sc;
    float Bc = bn1_b[t] - m * A;
    A1B1[t] = A; A1B1[128 + t] = Bc;
    __shared__ float Bs[128];
    Bs[t] = Bc;
    for (int j = 0; j < 32; j++) effW1[t * 32 + j] = W1[t * 32 + j] * A;
    for (int j = 0; j < 32; j++) W2T[t * 32 + j] = W2[j * 128 + t];
    __syncthreads();
    if (t < 32) {
        float s = b1[t];
        for (int c = 0; c < 128; c++) s += W1[c * 32 + t] * Bs[c];
        effb1[t] = s;
    }
}

// ---------------------------------------------------------------------------
// K6: f1[b,p,j] = gelu( sum_c effW1[c][j]*y1[b,c,p] + effb1[j] ). 1024 blocks.
__global__ void k_ffn1(const float* __restrict__ y1, const float* __restrict__ effW1,
                       const float* __restrict__ effb1, float* __restrict__ f1) {
    int gp = blockIdx.x * 256 + threadIdx.x;
    int b = gp >> 14, p = gp & 16383;
    const float* col = y1 + (size_t)b * (CC * (size_t)LL) + p;
    float acc[32];
    #pragma unroll
    for (int j = 0; j < 32; j++) acc[j] = effb1[j];
    for (int c = 0; c < CC; c++) {
        float v = col[(size_t)c * LL];
        const float4* w4 = (const float4*)(effW1 + c * 32);
        #pragma unroll
        for (int i = 0; i < 8; i++) {
            float4 w = w4[i];
            acc[4*i+0] += w.x * v; acc[4*i+1] += w.y * v;
            acc[4*i+2] += w.z * v; acc[4*i+3] += w.w * v;
        }
    }
    float4* dst = (float4*)(f1 + (size_t)gp * 32);
    #pragma unroll
    for (int i = 0; i < 8; i++) {
        float4 o4;
        o4.x = gelu_f(acc[4*i+0]); o4.y = gelu_f(acc[4*i+1]);
        o4.z = gelu_f(acc[4*i+2]); o4.w = gelu_f(acc[4*i+3]);
        dst[i] = o4;
    }
}

// ---------------------------------------------------------------------------
// K7: f2 = gelu(f1@W2+b2); y2 = wn0*f2 + wn1*(y1*A1+B1). Writes raw y2 to out.
__global__ void k_ffn2(const float* __restrict__ f1, const float* __restrict__ W2T,
                       const float* __restrict__ b2, const float* __restrict__ y1,
                       const float* __restrict__ A1B1, const float* __restrict__ ffn_add_w,
                       float* __restrict__ outb) {
    int gp = blockIdx.x * 256 + threadIdx.x;
    int b = gp >> 14, p = gp & 16383;
    float f[32];
    {
        const float4* src = (const float4*)(f1 + (size_t)gp * 32);
        #pragma unroll
        for (int i = 0; i < 8; i++) {
            float4 v = src[i];
            f[4*i+0] = v.x; f[4*i+1] = v.y; f[4*i+2] = v.z; f[4*i+3] = v.w;
        }
    }
    float wa0 = ffn_add_w[0], wa1 = ffn_add_w[1];
    float r0 = fmaxf(wa0, 0.f), r1 = fmaxf(wa1, 0.f);
    float inv = 1.f / (r0 + r1 + 1e-12f);
    float wn0 = r0 * inv, wn1 = r1 * inv;
    const float* ycol = y1 + (size_t)b * (CC * (size_t)LL) + p;
    float* ocol = outb + (size_t)b * (CC * (size_t)LL) + p;
    for (int c = 0; c < CC; c++) {
        const float4* w4 = (const float4*)(W2T + c * 32);
        float a = b2[c];
        #pragma unroll
        for (int i = 0; i < 8; i++) {
            float4 w = w4[i];
            a += w.x * f[4*i+0] + w.y * f[4*i+1] + w.z * f[4*i+2] + w.w * f[4*i+3];
        }
        float f2 = gelu_f(a);
        float attv = ycol[(size_t)c * LL] * A1B1[c] + A1B1[128 + c];
        ocol[(size_t)c * LL] = wn0 * f2 + wn1 * attv;
    }
}

// fin2: final BN affine. 1 block, 128 threads.
__global__ void k_fin2(const float* __restrict__ stats2, const float* __restrict__ g,
                       const float* __restrict__ bb, float* __restrict__ A2B2) {
    int t = threadIdx.x;
    const float N = 262144.f;
    float m = stats2[t * 2] / N;
    float v = stats2[t * 2 + 1] / N - m * m;
    float sc = rsqrtf(v + 1e-5f);
    float A = g[t] * sc;
    A2B2[t] = A;
    A2B2[128 + t] = bb[t] - m * A;
}

// K10: in-place normalize d_out. 32768 blocks.
__global__ void k_norm(float* __restrict__ out, const float* __restrict__ A2B2) {
    size_t i = ((size_t)blockIdx.x * 256 + threadIdx.x) * 4;
    int c = (int)((i >> 14) & 127);
    float A = A2B2[c], Bc = A2B2[128 + c];
    float4 v = *(float4*)(out + i);
    v.x = v.x * A + Bc; v.y = v.y * A + Bc; v.z = v.z * A + Bc; v.w = v.w * A + Bc;
    *(float4*)(out + i) = v;
}

// ---------------------------------------------------------------------------
extern "C" void kernel_launch(void* const* d_in, const int* in_sizes, int n_in,
                              void* d_out, int out_size, void* d_ws, size_t ws_size,
                              hipStream_t stream) {
    const float* x        = (const float*)d_in[0];
    const float* dw_w     = (const float*)d_in[1];
    const float* bn2_g    = (const float*)d_in[2];
    const float* bn2_b    = (const float*)d_in[3];
    const float* pw_w     = (const float*)d_in[4];
    const float* pw_b     = (const float*)d_in[5];
    const float* add_w    = (const float*)d_in[6];
    const float* bn1_g    = (const float*)d_in[7];
    const float* bn1_b    = (const float*)d_in[8];
    const float* W1       = (const float*)d_in[9];
    const float* b1       = (const float*)d_in[10];
    const float* W2       = (const float*)d_in[11];
    const float* b2       = (const float*)d_in[12];
    const float* ffn_aw   = (const float*)d_in[13];
    const float* ffn_bn_g = (const float*)d_in[14];
    const float* ffn_bn_b = (const float*)d_in[15];

    float* w = (float*)d_ws;
    size_t off = 0;
    auto alloc = [&](size_t n) { float* p = w + off; off += n; return p; };
    // zero-init accumulator region (contiguous, single memset)
    float* dwstats = alloc(768);
    float* stats1  = alloc(256);
    float* stats2  = alloc(256);
    float* kv_un   = alloc(32768);
    float* ssum    = alloc(2048);
    size_t zero_bytes = off * sizeof(float);
    float* effW_t = alloc(49152);
    float* effB   = alloc(384);
    float* kvb    = alloc(32768);
    float* A1B1   = alloc(256);
    float* effW1  = alloc(4096);
    float* effb1  = alloc(32);
    float* W2T    = alloc(4096);
    float* A2B2   = alloc(256);
    float* y1     = alloc((size_t)BB * CC * LL);
    float* kbuf   = alloc((size_t)BB * LK * CC);
    float* vbuf   = alloc((size_t)BB * LK * CC);
    float* f1     = alloc((size_t)BB * LL * 32);
    (void)ws_size;

    float* outf = (float*)d_out;

    hipMemsetAsync(d_ws, 0, zero_bytes, stream);

    k_dw_stats<<<6144, 256, 0, stream>>>(x, dw_w, dwstats);
    k_finalize_dw<<<384, 128, 0, stream>>>(dwstats, pw_w, pw_b, bn2_g, bn2_b, effW_t, effB);
    k_branch_kv<<<2048, 256, 0, stream>>>(x, dw_w, effW_t, effB, kbuf, vbuf);
    k_kv_accum<<<512, 256, 0, stream>>>(kbuf, vbuf, kv_un, ssum);
    k_kv_div<<<128, 256, 0, stream>>>(kv_un, ssum, kvb);
    k_branch_q<<<4096, 256, 0, stream>>>(x, dw_w, effW_t, effB, kvb, add_w, y1);
    k_chan_stats<<<4096, 256, 0, stream>>>(y1, stats1);
    k_fin1<<<1, 128, 0, stream>>>(stats1, bn1_g, bn1_b, W1, b1, W2, A1B1, effW1, effb1, W2T);
    k_ffn1<<<1024, 256, 0, stream>>>(y1, effW1, effb1, f1);
    k_ffn2<<<1024, 256, 0, stream>>>(f1, W2T, b2, y1, A1B1, ffn_aw, outf);
    k_chan_stats<<<4096, 256, 0, stream>>>(outf, stats2);
    k_fin2<<<1, 128, 0, stream>>>(stats2, ffn_bn_g, ffn_bn_b, A2B2);
    k_norm<<<32768, 256, 0, stream>>>(outf, A2B2);
}

// Round 2
// 942.253 us; speedup vs baseline: 2.0051x; 2.0051x over previous
//
#include <hip/hip_runtime.h>
#include <hip/hip_bf16.h>
#include <math.h>

#define BB 16
#define CC 128
#define LL 16384
#define SS 128
#define LK 4096
#define NHEAD 8
#define DH 16

typedef __attribute__((ext_vector_type(8))) short short8;
typedef __attribute__((ext_vector_type(4))) float f32x4;

__device__ __forceinline__ float gelu_f(float x) {
    return 0.5f * x * (1.0f + erff(x * 0.70710678118654752f));
}

__device__ __forceinline__ ushort f2bf(float f) {
    __hip_bfloat16 h = __float2bfloat16(f);
    return *(ushort*)&h;
}
__device__ __forceinline__ float bf2f(ushort u) {
    union { unsigned int i; float f; } x; x.i = ((unsigned int)u) << 16; return x.f;
}

// Reduce s1,s2 across the block; result valid in thread 0.
__device__ __forceinline__ void block_reduce2(float& s1, float& s2) {
    #pragma unroll
    for (int off = 32; off; off >>= 1) {
        s1 += __shfl_down(s1, off);
        s2 += __shfl_down(s2, off);
    }
    __shared__ float red[2][4];
    int wid = threadIdx.x >> 6, lid = threadIdx.x & 63;
    if (lid == 0) { red[0][wid] = s1; red[1][wid] = s2; }
    __syncthreads();
    if (threadIdx.x == 0) {
        int nw = blockDim.x >> 6;
        float a = 0.f, b = 0.f;
        for (int i = 0; i < nw; i++) { a += red[0][i]; b += red[1][i]; }
        s1 = a; s2 = b;
    }
}

// ---------------------------------------------------------------------------
// K_dw: depthwise 3x3 for all 3 branches. Block = (b, oh, cg): stages x rows
// oh-1..oh+1 for 32 channels in LDS, computes q row (128 ow); even oh also
// computes k,v stride-2 row oh/2 (64 ow'). Outputs bf16 [b][cg][p][c32].
__global__ __launch_bounds__(256) void k_dw(const float* __restrict__ x,
        const float* __restrict__ dw_w,
        ushort* __restrict__ dwq, ushort* __restrict__ dwk, ushort* __restrict__ dwv) {
    int bx = blockIdx.x;
    int cg = bx & 3;
    int oh = (bx >> 2) & 127;
    int b  = bx >> 9;
    __shared__ float xs[3][32][132];
    __shared__ float wls[3][32][9];
    int tid = threadIdx.x;
    for (int i = tid; i < 864; i += 256) {
        int br = i / 288; int rem = i - br * 288; int c = rem / 9; int tap = rem - c * 9;
        wls[br][c][tap] = dw_w[(br * CC + cg * 32 + c) * 9 + tap];
    }
    for (int i = tid; i < 3 * 32 * 32; i += 256) {
        int r = i >> 10;
        int rem = i & 1023;
        int c = rem >> 5;
        int f4 = rem & 31;
        int ih = oh - 1 + r;
        float4 v = make_float4(0.f, 0.f, 0.f, 0.f);
        if (ih >= 0 && ih < 128)
            v = *(const float4*)(x + ((size_t)b * CC + cg * 32 + c) * (size_t)LL + ih * SS + f4 * 4);
        *(float4*)&xs[r][c][f4 * 4] = v;
    }
    __syncthreads();
    int owb = tid & 63;
    int q4 = tid >> 6;          // channel sub-group: c = q4*8 .. q4*8+7
    union { ushort u[8]; float4 v; } pk;
    // q branch: ow = owb and owb+64
    #pragma unroll
    for (int pass = 0; pass < 2; pass++) {
        int ow = owb + pass * 64;
        #pragma unroll
        for (int cc = 0; cc < 8; cc++) {
            int c = q4 * 8 + cc;
            float acc = 0.f;
            #pragma unroll
            for (int r = 0; r < 3; r++) {
                #pragma unroll
                for (int d = 0; d < 3; d++) {
                    int iw = ow + d - 1;
                    if (iw >= 0 && iw < 128) acc += wls[0][c][r * 3 + d] * xs[r][c][iw];
                }
            }
            pk.u[cc] = f2bf(acc);
        }
        *(float4*)(dwq + ((((size_t)b * 4 + cg) * LL) + oh * 128 + ow) * 32 + q4 * 8) = pk.v;
    }
    // k,v branches (stride 2) when oh even
    if ((oh & 1) == 0) {
        int ohp = oh >> 1;
        int owp = owb;
        #pragma unroll
        for (int br = 1; br <= 2; br++) {
            #pragma unroll
            for (int cc = 0; cc < 8; cc++) {
                int c = q4 * 8 + cc;
                float acc = 0.f;
                #pragma unroll
                for (int r = 0; r < 3; r++) {
                    #pragma unroll
                    for (int d = 0; d < 3; d++) {
                        int iw = 2 * owp + d - 1;
                        if (iw >= 0) acc += wls[br][c][r * 3 + d] * xs[r][c][iw];
                    }
                }
                pk.u[cc] = f2bf(acc);
            }
            ushort* dst = (br == 1) ? dwk : dwv;
            *(float4*)(dst + ((((size_t)b * 4 + cg) * LK) + ohp * 64 + owp) * 32 + q4 * 8) = pk.v;
        }
    }
}

// ---------------------------------------------------------------------------
// Stats over dw buffers: per (branch, channel) sum/sumsq.
__global__ __launch_bounds__(256) void k_stats_dw(const ushort* __restrict__ dwq,
        const ushort* __restrict__ dwk, const ushort* __restrict__ dwv,
        float* __restrict__ stats /*[3][128][2]*/) {
    int bx = blockIdx.x;
    int br, b, cg, rows;
    const ushort* base;
    if (bx < 256) {
        br = 0; b = bx >> 4; cg = (bx >> 2) & 3; int chunk = bx & 3;
        base = dwq + (((size_t)b * 4 + cg) * LL + chunk * 4096) * 32; rows = 4096;
    } else {
        int i = bx - 256; br = 1 + (i >> 6); int j = i & 63; b = j >> 2; cg = j & 3;
        base = ((br == 1) ? dwk : dwv) + (((size_t)b * 4 + cg) * LK) * 32; rows = 4096;
    }
    int tid = threadIdx.x;
    int quad = tid & 3;
    float s1[8], s2[8];
    #pragma unroll
    for (int i = 0; i < 8; i++) { s1[i] = 0.f; s2[i] = 0.f; }
    for (int r = tid >> 2; r < rows; r += 64) {
        union { ushort u[8]; float4 v; } pk;
        pk.v = *(const float4*)(base + (size_t)r * 32 + quad * 8);
        #pragma unroll
        for (int i = 0; i < 8; i++) { float f = bf2f(pk.u[i]); s1[i] += f; s2[i] += f * f; }
    }
    __shared__ float a1[32], a2[32];
    if (tid < 32) { a1[tid] = 0.f; a2[tid] = 0.f; }
    __syncthreads();
    #pragma unroll
    for (int i = 0; i < 8; i++) {
        atomicAdd(&a1[quad * 8 + i], s1[i]);
        atomicAdd(&a2[quad * 8 + i], s2[i]);
    }
    __syncthreads();
    if (tid < 32) {
        atomicAdd(&stats[(br * CC + cg * 32 + tid) * 2 + 0], a1[tid]);
        atomicAdd(&stats[(br * CC + cg * 32 + tid) * 2 + 1], a2[tid]);
    }
}

// ---------------------------------------------------------------------------
// Fold BN2d into pointwise: effWb[br][o][c] bf16, effB[br][o] fp32.
__global__ void k_finalize_dw(const float* __restrict__ stats, const float* __restrict__ pw_w,
                              const float* __restrict__ pw_b, const float* __restrict__ bn2_g,
                              const float* __restrict__ bn2_b,
                              ushort* __restrict__ effWb, float* __restrict__ effB) {
    int br = blockIdx.x >> 7;
    int o  = blockIdx.x & 127;
    int c  = threadIdx.x;
    float N = (br == 0) ? 262144.f : 65536.f;
    float s1 = stats[(br * CC + c) * 2 + 0];
    float s2 = stats[(br * CC + c) * 2 + 1];
    float m = s1 / N;
    float v = s2 / N - m * m;
    float sc = rsqrtf(v + 1e-5f);
    float A  = bn2_g[br * CC + c] * sc;
    float Bc = bn2_b[br * CC + c] - m * A;
    float w  = pw_w[((size_t)br * CC + o) * CC + c];
    effWb[((size_t)br * CC + o) * CC + c] = f2bf(w * A);
    float pb = w * Bc, dummy = 0.f;
    block_reduce2(pb, dummy);
    if (threadIdx.x == 0) effB[br * CC + o] = pw_b[br * CC + o] + pb;
}

// ---------------------------------------------------------------------------
// GEMM for k/v branches: [128p x 128c] x [128c x 128o], epilogue gelu,
// write fp32 [b][p][c]. grid 1024 (brv, b, ptile).
__global__ __launch_bounds__(256) void k_gemm_kv(const ushort* __restrict__ dwk,
        const ushort* __restrict__ dwv, const ushort* __restrict__ effWb,
        const float* __restrict__ effB, float* __restrict__ kbuf, float* __restrict__ vbuf) {
    __shared__ __align__(16) char raw[69632];
    short* As = (short*)raw;            // [128][136]
    short* Bs = (short*)(raw + 34816);  // [128][136]
    float* Sf = (float*)raw;            // [128][132]
    int bx = blockIdx.x;
    int brv = bx >> 9;
    int b = (bx >> 5) & 15;
    int p0 = (bx & 31) * 128;
    const ushort* dw = brv ? dwv : dwk;
    const ushort* Wg = effWb + (size_t)(1 + brv) * CC * CC;
    int tid = threadIdx.x;
    for (int i = tid; i < 2048; i += 256) {
        int row = i >> 4; int f4 = i & 15; int cg = f4 >> 2;
        float4 v = *(const float4*)(dw + (((size_t)b * 4 + cg) * LK + p0 + row) * 32 + (f4 & 3) * 8);
        *(float4*)&As[row * 136 + f4 * 8] = v;
    }
    for (int i = tid; i < 2048; i += 256) {
        int row = i >> 4; int f4 = i & 15;
        float4 v = *(const float4*)(Wg + (size_t)row * 128 + f4 * 8);
        *(float4*)&Bs[row * 136 + f4 * 8] = v;
    }
    __syncthreads();
    int w = tid >> 6, l = tid & 63;
    int m0 = w * 32;
    int la = l & 15, lb = l >> 4;
    f32x4 acc[2][8];
    #pragma unroll
    for (int i = 0; i < 2; i++)
        #pragma unroll
        for (int j = 0; j < 8; j++) acc[i][j] = (f32x4){0.f, 0.f, 0.f, 0.f};
    #pragma unroll
    for (int kt = 0; kt < 4; kt++) {
        int kb = kt * 32 + lb * 8;
        short8 a0 = *(const short8*)&As[(m0 + la) * 136 + kb];
        short8 a1 = *(const short8*)&As[(m0 + 16 + la) * 136 + kb];
        #pragma unroll
        for (int nt = 0; nt < 8; nt++) {
            short8 bf = *(const short8*)&Bs[(nt * 16 + la) * 136 + kb];
            acc[0][nt] = __builtin_amdgcn_mfma_f32_16x16x32_bf16(a0, bf, acc[0][nt], 0, 0, 0);
            acc[1][nt] = __builtin_amdgcn_mfma_f32_16x16x32_bf16(a1, bf, acc[1][nt], 0, 0, 0);
        }
    }
    __syncthreads();
    float bias[8];
    #pragma unroll
    for (int nt = 0; nt < 8; nt++) bias[nt] = effB[(1 + brv) * CC + nt * 16 + la];
    #pragma unroll
    for (int mt = 0; mt < 2; mt++)
        #pragma unroll
        for (int nt = 0; nt < 8; nt++)
            #pragma unroll
            for (int i = 0; i < 4; i++) {
                float vv = acc[mt][nt][i] + bias[nt];
                Sf[(m0 + mt * 16 + lb * 4 + i) * 132 + nt * 16 + la] = gelu_f(vv);
            }
    __syncthreads();
    float* outb = (brv ? vbuf : kbuf) + ((size_t)b * LK + p0) * CC;
    for (int i = tid; i < 4096; i += 256) {
        int row = i >> 5; int c4 = i & 31;
        *(float4*)(outb + (size_t)row * CC + c4 * 4) = *(const float4*)&Sf[row * 132 + c4 * 4];
    }
}

// ---------------------------------------------------------------------------
// kv accumulation (softmax over sequence): unchanged from round 1.
__global__ void k_kv_accum(const float* __restrict__ k_buf, const float* __restrict__ v_buf,
                           float* __restrict__ kv_un, float* __restrict__ ssum) {
    int bx = blockIdx.x;
    int b = bx >> 5;
    int h = (bx >> 2) & 7;
    int sl = bx & 3;
    int n0 = sl * 1024;
    __shared__ float kch[64][16];
    __shared__ float vch[64][16];
    int tid = threadIdx.x;
    int d = tid >> 4, e = tid & 15;
    float acc = 0.f, ss = 0.f;
    for (int ch = 0; ch < 16; ch++) {
        int base = n0 + ch * 64;
        {
            int rr = tid >> 2, c4 = (tid & 3) * 4;
            const float* kp = k_buf + ((size_t)b * LK + base + rr) * CC + h * DH + c4;
            const float* vp = v_buf + ((size_t)b * LK + base + rr) * CC + h * DH + c4;
            float4 kf = *(const float4*)kp;
            float4 vf = *(const float4*)vp;
            kch[rr][c4+0] = __expf(kf.x); kch[rr][c4+1] = __expf(kf.y);
            kch[rr][c4+2] = __expf(kf.z); kch[rr][c4+3] = __expf(kf.w);
            vch[rr][c4+0] = vf.x; vch[rr][c4+1] = vf.y;
            vch[rr][c4+2] = vf.z; vch[rr][c4+3] = vf.w;
        }
        __syncthreads();
        #pragma unroll 8
        for (int rr = 0; rr < 64; rr++) {
            float ek = kch[rr][d];
            acc += ek * vch[rr][e];
            ss += ek;
        }
        __syncthreads();
    }
    atomicAdd(&kv_un[(((size_t)b * NHEAD + h) * DH + d) * DH + e], acc);
    if (e == 0) atomicAdd(&ssum[((size_t)b * NHEAD + h) * DH + d], ss);
}

__global__ void k_kv_div(const float* __restrict__ kv_un, const float* __restrict__ ssum,
                         float* __restrict__ kv) {
    int i = blockIdx.x * 256 + threadIdx.x;
    kv[i] = kv_un[i] / ssum[i >> 4];
}

// ---------------------------------------------------------------------------
// GEMM for q branch + gelu + softmax(dh) + attention + residual. grid 2048.
__global__ __launch_bounds__(256) void k_gemm_q(const ushort* __restrict__ dwq,
        const ushort* __restrict__ effWb, const float* __restrict__ effB,
        const float* __restrict__ kvb, const float* __restrict__ add_w,
        const float* __restrict__ x, float* __restrict__ y1) {
    __shared__ __align__(16) char raw[69632];
    short* As = (short*)raw;            // [128][136]
    short* Bs = (short*)(raw + 34816);  // [128][136]
    float* Sf = (float*)raw;            // [128][133]
    __shared__ float kvs[2048];
    int bx = blockIdx.x;
    int b = bx >> 7;
    int p0 = (bx & 127) * 128;
    int tid = threadIdx.x;
    for (int i = tid; i < 512; i += 256)
        *(float4*)&kvs[i * 4] = *(const float4*)(kvb + (size_t)b * 2048 + i * 4);
    for (int i = tid; i < 2048; i += 256) {
        int row = i >> 4; int f4 = i & 15; int cg = f4 >> 2;
        float4 v = *(const float4*)(dwq + (((size_t)b * 4 + cg) * LL + p0 + row) * 32 + (f4 & 3) * 8);
        *(float4*)&As[row * 136 + f4 * 8] = v;
    }
    for (int i = tid; i < 2048; i += 256) {
        int row = i >> 4; int f4 = i & 15;
        float4 v = *(const float4*)(effWb + (size_t)row * 128 + f4 * 8);
        *(float4*)&Bs[row * 136 + f4 * 8] = v;
    }
    __syncthreads();
    int w = tid >> 6, l = tid & 63;
    int m0 = w * 32;
    int la = l & 15, lb = l >> 4;
    f32x4 acc[2][8];
    #pragma unroll
    for (int i = 0; i < 2; i++)
        #pragma unroll
        for (int j = 0; j < 8; j++) acc[i][j] = (f32x4){0.f, 0.f, 0.f, 0.f};
    #pragma unroll
    for (int kt = 0; kt < 4; kt++) {
        int kb = kt * 32 + lb * 8;
        short8 a0 = *(const short8*)&As[(m0 + la) * 136 + kb];
        short8 a1 = *(const short8*)&As[(m0 + 16 + la) * 136 + kb];
        #pragma unroll
        for (int nt = 0; nt < 8; nt++) {
            short8 bf = *(const short8*)&Bs[(nt * 16 + la) * 136 + kb];
            acc[0][nt] = __builtin_amdgcn_mfma_f32_16x16x32_bf16(a0, bf, acc[0][nt], 0, 0, 0);
            acc[1][nt] = __builtin_amdgcn_mfma_f32_16x16x32_bf16(a1, bf, acc[1][nt], 0, 0, 0);
        }
    }
    __syncthreads();
    float bias[8];
    #pragma unroll
    for (int nt = 0; nt < 8; nt++) bias[nt] = effB[nt * 16 + la];
    #pragma unroll
    for (int mt = 0; mt < 2; mt++)
        #pragma unroll
        for (int nt = 0; nt < 8; nt++)
            #pragma unroll
            for (int i = 0; i < 4; i++) {
                float vv = acc[mt][nt][i] + bias[nt];
                Sf[(m0 + mt * 16 + lb * 4 + i) * 133 + nt * 16 + la] = gelu_f(vv);
            }
    __syncthreads();
    // attention epilogue: thread = (p, head-group)
    int p = tid & 127;
    int hg = tid >> 7;
    float wa0 = add_w[0], wa1 = add_w[1];
    float r0 = fmaxf(wa0, 0.f), r1 = fmaxf(wa1, 0.f);
    float inv = 1.f / (r0 + r1 + 1e-12f);
    float wn0 = r0 * inv, wn1 = r1 * inv;
    const float* xb = x + (size_t)b * CC * (size_t)LL + p0 + p;
    float* yb = y1 + (size_t)b * CC * (size_t)LL + p0 + p;
    #pragma unroll
    for (int hh = 0; hh < 4; hh++) {
        int h = hg * 4 + hh;
        float sv[16];
        float mx = -1e30f;
        #pragma unroll
        for (int d = 0; d < 16; d++) { sv[d] = Sf[p * 133 + h * 16 + d]; mx = fmaxf(mx, sv[d]); }
        float s = 0.f;
        #pragma unroll
        for (int d = 0; d < 16; d++) { sv[d] = __expf(sv[d] - mx); s += sv[d]; }
        float is = 1.f / s;
        #pragma unroll
        for (int e = 0; e < 16; e++) {
            float att = 0.f;
            #pragma unroll
            for (int d = 0; d < 16; d++) att += sv[d] * kvs[(h * 16 + d) * 16 + e];
            int c = h * 16 + e;
            yb[(size_t)c * LL] = wn0 * att * is + wn1 * xb[(size_t)c * LL];
        }
    }
}

// ---------------------------------------------------------------------------
// Per-channel sum/sumsq over [B][C][L]. grid 4096.
__global__ void k_chan_stats(const float* __restrict__ buf, float* __restrict__ stats) {
    int c = blockIdx.x >> 5;
    int s = blockIdx.x & 31;
    int b = s >> 1;
    int p0 = (s & 1) << 13;
    const float* src = buf + (size_t)b * (CC * (size_t)LL) + (size_t)c * LL + p0;
    float s1 = 0.f, s2 = 0.f;
    for (int i = threadIdx.x * 4; i < 8192; i += 1024) {
        float4 v = *(const float4*)(src + i);
        s1 += v.x + v.y + v.z + v.w;
        s2 += v.x * v.x + v.y * v.y + v.z * v.z + v.w * v.w;
    }
    block_reduce2(s1, s2);
    if (threadIdx.x == 0) {
        atomicAdd(&stats[c * 2 + 0], s1);
        atomicAdd(&stats[c * 2 + 1], s2);
    }
}

// ---------------------------------------------------------------------------
__global__ void k_fin1(const float* __restrict__ stats1, const float* __restrict__ bn1_g,
                       const float* __restrict__ bn1_b, const float* __restrict__ W1,
                       const float* __restrict__ b1, const float* __restrict__ W2,
                       float* __restrict__ A1B1, float* __restrict__ effW1,
                       float* __restrict__ effb1, float* __restrict__ W2T) {
    int t = threadIdx.x;
    const float N = 262144.f;
    float m = stats1[t * 2] / N;
    float v = stats1[t * 2 + 1] / N - m * m;
    float sc = rsqrtf(v + 1e-5f);
    float A = bn1_g[t] * sc;
    float Bc = bn1_b[t] - m * A;
    A1B1[t] = A; A1B1[128 + t] = Bc;
    __shared__ float Bs[128];
    Bs[t] = Bc;
    for (int j = 0; j < 32; j++) effW1[t * 32 + j] = W1[t * 32 + j] * A;
    for (int j = 0; j < 32; j++) W2T[t * 32 + j] = W2[j * 128 + t];
    __syncthreads();
    if (t < 32) {
        float s = b1[t];
        for (int c = 0; c < 128; c++) s += W1[c * 32 + t] * Bs[c];
        effb1[t] = s;
    }
}

// ---------------------------------------------------------------------------
// FFN1: f1[b,p,j] = gelu(sum_c effW1[c][j]*y1[b,c,p] + effb1[j]); LDS weights.
__global__ __launch_bounds__(256) void k_ffn1(const float* __restrict__ y1,
        const float* __restrict__ effW1, const float* __restrict__ effb1,
        float* __restrict__ f1) {
    __shared__ float wl[4096];
    __shared__ float bl[32];
    int tid = threadIdx.x;
    for (int i = tid; i < 4096; i += 256) wl[i] = effW1[i];
    if (tid < 32) bl[tid] = effb1[tid];
    __syncthreads();
    int gp = blockIdx.x * 256 + tid;
    int b = gp >> 14, p = gp & 16383;
    const float* col = y1 + (size_t)b * (CC * (size_t)LL) + p;
    float acc[32];
    #pragma unroll
    for (int j = 0; j < 32; j++) acc[j] = bl[j];
    for (int c = 0; c < CC; c++) {
        float v = col[(size_t)c * LL];
        const float4* w4 = (const float4*)&wl[c * 32];
        #pragma unroll
        for (int i = 0; i < 8; i++) {
            float4 w = w4[i];
            acc[4*i+0] += w.x * v; acc[4*i+1] += w.y * v;
            acc[4*i+2] += w.z * v; acc[4*i+3] += w.w * v;
        }
    }
    float4* dst = (float4*)(f1 + (size_t)gp * 32);
    #pragma unroll
    for (int i = 0; i < 8; i++) {
        float4 o4;
        o4.x = gelu_f(acc[4*i+0]); o4.y = gelu_f(acc[4*i+1]);
        o4.z = gelu_f(acc[4*i+2]); o4.w = gelu_f(acc[4*i+3]);
        dst[i] = o4;
    }
}

// ---------------------------------------------------------------------------
// FFN2: f2 = gelu(f1@W2+b2); out = wn0*f2 + wn1*(y1*A1+B1); LDS weights.
__global__ __launch_bounds__(256) void k_ffn2(const float* __restrict__ f1,
        const float* __restrict__ W2T, const float* __restrict__ b2,
        const float* __restrict__ y1, const float* __restrict__ A1B1,
        const float* __restrict__ ffn_add_w, float* __restrict__ outb) {
    __shared__ float wl[4096];
    __shared__ float b2l[128];
    __shared__ float abl[256];
    int tid = threadIdx.x;
    for (int i = tid; i < 4096; i += 256) wl[i] = W2T[i];
    if (tid < 128) b2l[tid] = b2[tid];
    if (tid >= 128) abl[tid - 128] = A1B1[tid - 128];
    if (tid < 128) abl[128 + tid] = A1B1[128 + tid];
    __syncthreads();
    int gp = blockIdx.x * 256 + tid;
    int b = gp >> 14, p = gp & 16383;
    float f[32];
    {
        const float4* src = (const float4*)(f1 + (size_t)gp * 32);
        #pragma unroll
        for (int i = 0; i < 8; i++) {
            float4 v = src[i];
            f[4*i+0] = v.x; f[4*i+1] = v.y; f[4*i+2] = v.z; f[4*i+3] = v.w;
        }
    }
    float wa0 = ffn_add_w[0], wa1 = ffn_add_w[1];
    float r0 = fmaxf(wa0, 0.f), r1 = fmaxf(wa1, 0.f);
    float inv = 1.f / (r0 + r1 + 1e-12f);
    float wn0 = r0 * inv, wn1 = r1 * inv;
    const float* ycol = y1 + (size_t)b * (CC * (size_t)LL) + p;
    float* ocol = outb + (size_t)b * (CC * (size_t)LL) + p;
    for (int c = 0; c < CC; c++) {
        const float4* w4 = (const float4*)&wl[c * 32];
        float a = b2l[c];
        #pragma unroll
        for (int i = 0; i < 8; i++) {
            float4 w = w4[i];
            a += w.x * f[4*i+0] + w.y * f[4*i+1] + w.z * f[4*i+2] + w.w * f[4*i+3];
        }
        float f2 = gelu_f(a);
        float attv = ycol[(size_t)c * LL] * abl[c] + abl[128 + c];
        ocol[(size_t)c * LL] = wn0 * f2 + wn1 * attv;
    }
}

__global__ void k_fin2(const float* __restrict__ stats2, const float* __restrict__ g,
                       const float* __restrict__ bb, float* __restrict__ A2B2) {
    int t = threadIdx.x;
    const float N = 262144.f;
    float m = stats2[t * 2] / N;
    float v = stats2[t * 2 + 1] / N - m * m;
    float sc = rsqrtf(v + 1e-5f);
    float A = g[t] * sc;
    A2B2[t] = A;
    A2B2[128 + t] = bb[t] - m * A;
}

__global__ void k_norm(float* __restrict__ out, const float* __restrict__ A2B2) {
    size_t i = ((size_t)blockIdx.x * 256 + threadIdx.x) * 4;
    int c = (int)((i >> 14) & 127);
    float A = A2B2[c], Bc = A2B2[128 + c];
    float4 v = *(float4*)(out + i);
    v.x = v.x * A + Bc; v.y = v.y * A + Bc; v.z = v.z * A + Bc; v.w = v.w * A + Bc;
    *(float4*)(out + i) = v;
}

// ---------------------------------------------------------------------------
extern "C" void kernel_launch(void* const* d_in, const int* in_sizes, int n_in,
                              void* d_out, int out_size, void* d_ws, size_t ws_size,
                              hipStream_t stream) {
    const float* x        = (const float*)d_in[0];
    const float* dw_w     = (const float*)d_in[1];
    const float* bn2_g    = (const float*)d_in[2];
    const float* bn2_b    = (const float*)d_in[3];
    const float* pw_w     = (const float*)d_in[4];
    const float* pw_b     = (const float*)d_in[5];
    const float* add_w    = (const float*)d_in[6];
    const float* bn1_g    = (const float*)d_in[7];
    const float* bn1_b    = (const float*)d_in[8];
    const float* W1       = (const float*)d_in[9];
    const float* b1       = (const float*)d_in[10];
    const float* W2       = (const float*)d_in[11];
    const float* b2       = (const float*)d_in[12];
    const float* ffn_aw   = (const float*)d_in[13];
    const float* ffn_bn_g = (const float*)d_in[14];
    const float* ffn_bn_b = (const float*)d_in[15];

    float* w = (float*)d_ws;
    size_t off = 0;
    auto alloc = [&](size_t n) { float* p = w + off; off += n; return p; };
    // zero-init accumulator region (contiguous, single memset)
    float* dwstats = alloc(768);
    float* stats1  = alloc(256);
    float* stats2  = alloc(256);
    float* kv_un   = alloc(32768);
    float* ssum    = alloc(2048);
    size_t zero_bytes = off * sizeof(float);
    float* effWb_f = alloc(24576);   // 3*128*128 bf16
    float* effB    = alloc(384);
    float* kvb     = alloc(32768);
    float* A1B1    = alloc(256);
    float* effW1   = alloc(4096);
    float* effb1   = alloc(32);
    float* W2T     = alloc(4096);
    float* A2B2    = alloc(256);
    float* y1      = alloc((size_t)BB * CC * LL);
    float* kbuf    = alloc((size_t)BB * LK * CC);
    float* vbuf    = alloc((size_t)BB * LK * CC);
    float* dwq_f   = alloc((size_t)BB * LL * CC / 2);   // bf16
    float* dwk_f   = alloc((size_t)BB * LK * CC / 2);
    float* dwv_f   = alloc((size_t)BB * LK * CC / 2);
    float* f1      = kbuf;   // alias: kbuf dead after k_kv_accum
    (void)ws_size;

    ushort* effWb = (ushort*)effWb_f;
    ushort* dwq = (ushort*)dwq_f;
    ushort* dwk = (ushort*)dwk_f;
    ushort* dwv = (ushort*)dwv_f;
    float* outf = (float*)d_out;

    hipMemsetAsync(d_ws, 0, zero_bytes, stream);

    k_dw<<<8192, 256, 0, stream>>>(x, dw_w, dwq, dwk, dwv);
    k_stats_dw<<<384, 256, 0, stream>>>(dwq, dwk, dwv, dwstats);
    k_finalize_dw<<<384, 128, 0, stream>>>(dwstats, pw_w, pw_b, bn2_g, bn2_b, effWb, effB);
    k_gemm_kv<<<1024, 256, 0, stream>>>(dwk, dwv, effWb, effB, kbuf, vbuf);
    k_kv_accum<<<512, 256, 0, stream>>>(kbuf, vbuf, kv_un, ssum);
    k_kv_div<<<128, 256, 0, stream>>>(kv_un, ssum, kvb);
    k_gemm_q<<<2048, 256, 0, stream>>>(dwq, effWb, effB, kvb, add_w, x, y1);
    k_chan_stats<<<4096, 256, 0, stream>>>(y1, stats1);
    k_fin1<<<1, 128, 0, stream>>>(stats1, bn1_g, bn1_b, W1, b1, W2, A1B1, effW1, effb1, W2T);
    k_ffn1<<<1024, 256, 0, stream>>>(y1, effW1, effb1, f1);
    k_ffn2<<<1024, 256, 0, stream>>>(f1, W2T, b2, y1, A1B1, ffn_aw, outf);
    k_chan_stats<<<4096, 256, 0, stream>>>(outf, stats2);
    k_fin2<<<1, 128, 0, stream>>>(stats2, ffn_bn_g, ffn_bn_b, A2B2);
    k_norm<<<32768, 256, 0, stream>>>(outf, A2B2);
}